// Round 7
// baseline (880.034 us; speedup 1.0000x reference)
//
#include <hip/hip_runtime.h>
#include <hip/hip_bf16.h>

#define N 8192

typedef _Float16 half_t;
typedef __attribute__((ext_vector_type(8))) _Float16 half8;
typedef __attribute__((ext_vector_type(4))) float f32x4;
typedef unsigned int uint;
typedef unsigned short ushort;

#define MFMA16(a, b, c) __builtin_amdgcn_mfma_f32_16x16x32_f16(a, b, c, 0, 0, 0)

// split: x = xh + xl * 2^-11 (residual stored x2048 to stay f16-normal)
#define RES_SCALE 2048.0f
#define RES_INV   (1.0f / 2048.0f)

union UH8 { int4 i; half8 h; };
__device__ __forceinline__ half8 ldh(const ushort* p) {
    UH8 t; t.i = *(const int4*)p; return t.h;
}
__device__ __forceinline__ ushort h2u(half_t h) {
    union { half_t f; ushort u; } c; c.f = h; return c.u;
}

__device__ __forceinline__ float wave_max(float v) {
#pragma unroll
    for (int o = 32; o > 0; o >>= 1) v = fmaxf(v, __shfl_xor(v, o, 64));
    return v;
}
__device__ __forceinline__ float wave_sum(float v) {
#pragma unroll
    for (int o = 32; o > 0; o >>= 1) v += __shfl_xor(v, o, 64);
    return v;
}

// ---------------------------------------------------------------------------
// Elementwise fp32 -> f16 split pair. n must be a multiple of 1024.
// ---------------------------------------------------------------------------
__global__ __launch_bounds__(256) void split_f16(
    const float* __restrict__ X, ushort* __restrict__ Xh, ushort* __restrict__ Xl)
{
    const size_t i = ((size_t)blockIdx.x * 256 + threadIdx.x) * 4;
    float4 v = *(const float4*)(X + i);
    ushort h[4], l[4];
#pragma unroll
    for (int t = 0; t < 4; ++t) {
        float f = (&v.x)[t];
        half_t hh = (half_t)f;
        half_t ll = (half_t)((f - (float)hh) * RES_SCALE);
        h[t] = h2u(hh); l[t] = h2u(ll);
    }
    *(ushort4*)(Xh + i) = make_ushort4(h[0], h[1], h[2], h[3]);
    *(ushort4*)(Xl + i) = make_ushort4(l[0], l[1], l[2], l[3]);
}

// ---------------------------------------------------------------------------
// MFMA MLP GEMM: C[M x Nc] = A[M x K] @ W[Nc x K]^T + bias, optional PReLU.
// f16 split-2 inputs, 3-term MFMA (hh + 2^-11(h*l + l*h)), fp32 accum.
// Block = 128 threads (2 waves), each wave 16 rows x 64 cols. No LDS.
// Grid (M/32, Nc/64). Emits fp32 C and/or split-f16 C.
// ---------------------------------------------------------------------------
__global__ __launch_bounds__(128) void gemm_f16s(
    const ushort* __restrict__ Ah, const ushort* __restrict__ Al,
    const ushort* __restrict__ Wh, const ushort* __restrict__ Wl,
    const float* __restrict__ bias, const float* __restrict__ slope_p,
    int Nc, int K, int act,
    float* __restrict__ Cf, ushort* __restrict__ Ch, ushort* __restrict__ Cl)
{
    const int w = threadIdx.x >> 6, lane = threadIdx.x & 63;
    const int l16 = lane & 15, lg = lane >> 4;
    const int row0 = blockIdx.x * 32 + w * 16;
    const int n0 = blockIdx.y * 64;
    f32x4 acc1[4], acc2[4];
#pragma unroll
    for (int c = 0; c < 4; ++c) {
        acc1[c] = (f32x4){0.f, 0.f, 0.f, 0.f};
        acc2[c] = (f32x4){0.f, 0.f, 0.f, 0.f};
    }
    for (int k0 = 0; k0 < K; k0 += 32) {
        const size_t aoff = (size_t)(row0 + l16) * K + lg * 8 + k0;
        half8 Af = ldh(Ah + aoff);
        half8 Alf = ldh(Al + aoff);
#pragma unroll
        for (int c = 0; c < 4; ++c) {
            const size_t woff = (size_t)(n0 + c * 16 + l16) * K + lg * 8 + k0;
            half8 Wf = ldh(Wh + woff);
            half8 Wlf = ldh(Wl + woff);
            acc1[c] = MFMA16(Af, Wf, acc1[c]);
            acc2[c] = MFMA16(Af, Wlf, acc2[c]);
            acc2[c] = MFMA16(Alf, Wf, acc2[c]);
        }
    }
    const float slope = *slope_p;
#pragma unroll
    for (int c = 0; c < 4; ++c) {
        const int col = n0 + c * 16 + l16;
        const float b = bias[col];
#pragma unroll
        for (int r = 0; r < 4; ++r) {
            const int row = row0 + lg * 4 + r;
            float v = fmaf(acc2[c][r], RES_INV, acc1[c][r]) + b;
            if (act) v = v > 0.f ? v : slope * v;
            const size_t off = (size_t)row * Nc + col;
            if (Cf) Cf[off] = v;
            if (Ch) {
                half_t hh = (half_t)v;
                half_t ll = (half_t)((v - (float)hh) * RES_SCALE);
                Ch[off] = h2u(hh); Cl[off] = h2u(ll);
            }
        }
    }
}

// ---------------------------------------------------------------------------
// Row softmax + normalize; emit f16 2-way split of u; accumulate s, trace.
// ---------------------------------------------------------------------------
__global__ __launch_bounds__(256) void row_softmax_u(
    const float* __restrict__ E, ushort* __restrict__ uh, ushort* __restrict__ ul,
    float* __restrict__ stats)
{
    const int w = threadIdx.x >> 6, lane = threadIdx.x & 63;
    __shared__ float sacc[4][64];
    __shared__ float tacc[4];
    float s_l = 0.f, t_w = 0.f;
    const int base = blockIdx.x * 16 + w * 4;
    for (int r = 0; r < 4; ++r) {
        const int row = base + r;
        float v = E[(size_t)row * 64 + lane];
        float mx = wave_max(v);
        float e = expf(v - mx);
        float tot = wave_sum(e);
        tot = __shfl(tot, 0, 64);
        float es = e / tot;
        float dd = wave_sum(es * es);
        dd = __shfl(dd, 0, 64);
        float uv = es / sqrtf(dd);   // max(.,1e-9) never binds: dd >= 1/64
        half_t h = (half_t)uv;
        half_t l = (half_t)((uv - (float)h) * RES_SCALE);
        const size_t idx = (size_t)row * 64 + lane;
        uh[idx] = h2u(h); ul[idx] = h2u(l);
        s_l += uv;
        float uu = wave_sum(uv * uv);
        if (lane == 0) t_w += uu;
    }
    sacc[w][lane] = s_l;
    if (lane == 0) tacc[w] = t_w;
    __syncthreads();
    if (threadIdx.x < 64) {
        float tot = sacc[0][threadIdx.x] + sacc[1][threadIdx.x] +
                    sacc[2][threadIdx.x] + sacc[3][threadIdx.x];
        atomicAdd(&stats[threadIdx.x], tot);
    }
    if (threadIdx.x == 0)
        atomicAdd(&stats[64], tacc[0] + tacc[1] + tacc[2] + tacc[3]);
}

// ---------------------------------------------------------------------------
// Transpose E -> Et f16 [64][8192] so PV B-frags are direct 16B loads.
// ---------------------------------------------------------------------------
__global__ __launch_bounds__(256) void trans_e(
    const float* __restrict__ E, ushort* __restrict__ Et)
{
    __shared__ ushort T[64][72];
    const int ib = blockIdx.x;
    const int r = threadIdx.x >> 2;
    const int c0 = (threadIdx.x & 3) * 16;
#pragma unroll
    for (int q = 0; q < 4; ++q) {
        float4 v = *(const float4*)(E + (size_t)(ib * 64 + r) * 64 + c0 + q * 4);
#pragma unroll
        for (int t = 0; t < 4; ++t)
            T[c0 + q * 4 + t][r] = h2u((half_t)((&v.x)[t]));
    }
    __syncthreads();
    const int c = threadIdx.x >> 2;
    const int j0 = (threadIdx.x & 3) * 16;
    const size_t go = (size_t)c * N + ib * 64 + j0;
    *(int4*)(Et + go)     = *(const int4*)&T[c][j0];
    *(int4*)(Et + go + 8) = *(const int4*)&T[c][j0 + 8];
}

// ---------------------------------------------------------------------------
// Max over off-diagonal of S = u u^T. 4-wave blocks: bx = 64-row i-strip
// (wave w owns 16 rows), by = 1024-col j-group. Upper-triangle skip at block
// and tile level. Per-block max -> maxbuf[by*128+bx] (no atomics).
// ---------------------------------------------------------------------------
__global__ __launch_bounds__(256) void pass_max_f16(
    const ushort* __restrict__ uh, const ushort* __restrict__ ul,
    float* __restrict__ maxbuf)
{
    const int bx = blockIdx.x;       // i-strip [0,128)
    const int by = blockIdx.y;       // j-group [0,8)
    const int bid = by * 128 + bx;
    const int w = threadIdx.x >> 6, lane = threadIdx.x & 63;
    const int l16 = lane & 15, lg = lane >> 4;
    __shared__ float red[4];
    if (by * 1024 + 1024 <= bx * 64) {   // whole block below diagonal
        if (threadIdx.x == 0) maxbuf[bid] = 0.f;
        return;
    }
    const int i0 = bx * 64 + w * 16;
    const size_t ao = (size_t)(i0 + l16) * 64 + lg * 8;
    const half8 Ah0 = ldh(uh + ao), Ah1 = ldh(uh + ao + 32);
    const half8 Al0 = ldh(ul + ao), Al1 = ldh(ul + ao + 32);
    float mx = 0.f;
    for (int jn = 0; jn < 64; ++jn) {
        const int j0 = by * 1024 + jn * 16;
        if (j0 + 16 <= i0) continue;     // tile fully below this wave's diagonal
        const size_t bo = (size_t)(j0 + l16) * 64 + lg * 8;
        half8 Bh0 = ldh(uh + bo), Bh1 = ldh(uh + bo + 32);
        half8 Bl0 = ldh(ul + bo), Bl1 = ldh(ul + bo + 32);
        f32x4 s1 = {0.f, 0.f, 0.f, 0.f};
        f32x4 s2 = {0.f, 0.f, 0.f, 0.f};
        s1 = MFMA16(Ah0, Bh0, s1); s1 = MFMA16(Ah1, Bh1, s1);
        s2 = MFMA16(Ah0, Bl0, s2); s2 = MFMA16(Ah1, Bl1, s2);
        s2 = MFMA16(Al0, Bh0, s2); s2 = MFMA16(Al1, Bh1, s2);
        const bool dt = (j0 == i0);
#pragma unroll
        for (int r = 0; r < 4; ++r) {
            float s = fmaf(s2[r], RES_INV, s1[r]);
            bool dg = dt && (lg * 4 + r == l16);
            mx = dg ? mx : fmaxf(mx, s);
        }
    }
    mx = wave_max(mx);
    if (lane == 0) red[w] = mx;
    __syncthreads();
    if (threadIdx.x == 0)
        maxbuf[bid] = fmaxf(fmaxf(red[0], red[1]), fmaxf(red[2], red[3]));
}

// Reduce block maxes -> M; m = (||s||^2 - trace) / N^2.
__global__ __launch_bounds__(256) void fin_m(
    const float* __restrict__ maxbuf, float* __restrict__ stats)
{
    const int t = threadIdx.x;
    float mx = 0.f;
    for (int i = t; i < 1024; i += 256) mx = fmaxf(mx, maxbuf[i]);
    mx = wave_max(mx);
    __shared__ float red[4];
    __shared__ float ssh;
    if ((t & 63) == 0) red[t >> 6] = mx;
    if (t < 64) {
        float s = stats[t];
        float ss = wave_sum(s * s);
        if (t == 0) ssh = ss;
    }
    __syncthreads();
    if (t == 0) {
        stats[65] = fmaxf(fmaxf(red[0], red[1]), fmaxf(red[2], red[3]));
        stats[66] = (ssh - stats[64]) * (1.0f / 67108864.0f);
    }
}

// ---------------------------------------------------------------------------
// Fused: S tiles (f16 split MFMA) -> transform -> P,N f16 -> wave-private LDS
// -> PV (plain f16 MFMA vs Et). Block = one 16-row i-tile x one js slice;
// 4 waves split the 32 jt, deterministic LDS combine at the end.
// __launch_bounds__(256,8): VGPR<=64 + 17.4KB LDS -> 8 blocks/CU (grid = 8/CU).
// ---------------------------------------------------------------------------
__global__ __launch_bounds__(256, 8) void pass_prop_f16(
    const ushort* __restrict__ uh, const ushort* __restrict__ ul,
    const ushort* __restrict__ Et, const float* __restrict__ stats,
    const float* __restrict__ ah_p, float* __restrict__ Pp, float* __restrict__ Pn)
{
    __shared__ ushort PNs[4][2][16][68];   // [wave][P/N][i-local][j-local], stride 68
    const int w = threadIdx.x >> 6, lane = threadIdx.x & 63;
    const int l16 = lane & 15, lg = lane >> 4;
    const int i0 = blockIdx.x * 16;
    const int js = blockIdx.y;
    const float m = stats[66];
    const float Mx = stats[65];
    const float inv_pd = 1.f / (Mx - m);
    const float c1 = -m * inv_pd;
    const float ninv_m = -1.f / m;
    const float a = *ah_p;
    const size_t ao = (size_t)(i0 + l16) * 64 + lg * 8;
    const half8 Ah0 = ldh(uh + ao), Ah1 = ldh(uh + ao + 32);
    const half8 Al0 = ldh(ul + ao), Al1 = ldh(ul + ao + 32);
    f32x4 accP[4], accN[4];
#pragma unroll
    for (int cs = 0; cs < 4; ++cs) {
        accP[cs] = (f32x4){0.f, 0.f, 0.f, 0.f};
        accN[cs] = (f32x4){0.f, 0.f, 0.f, 0.f};
    }
    ushort (*myP)[68] = PNs[w][0];
    ushort (*myN)[68] = PNs[w][1];
    for (int t = 0; t < 8; ++t) {
        const int j0 = (js * 32 + t * 4 + w) * 64;
        // ---- S tiles -> transform -> f16 P,N into wave-private LDS ----
#pragma unroll
        for (int jn = 0; jn < 4; ++jn) {
            const size_t bo = (size_t)(j0 + jn * 16 + l16) * 64 + lg * 8;
            half8 Bh0 = ldh(uh + bo), Bh1 = ldh(uh + bo + 32);
            half8 Bl0 = ldh(ul + bo), Bl1 = ldh(ul + bo + 32);
            f32x4 s1 = {0.f, 0.f, 0.f, 0.f};
            f32x4 s2 = {0.f, 0.f, 0.f, 0.f};
            s1 = MFMA16(Ah0, Bh0, s1); s1 = MFMA16(Ah1, Bh1, s1);
            s2 = MFMA16(Ah0, Bl0, s2); s2 = MFMA16(Ah1, Bl1, s2);
            s2 = MFMA16(Al0, Bh0, s2); s2 = MFMA16(Al1, Bh1, s2);
            const bool dt = (j0 + jn * 16 == i0);
#pragma unroll
            for (int r = 0; r < 4; ++r) {
                float s = fmaf(s2[r], RES_INV, s1[r]);
                // l = (s-m > 0) ? (s-m)/(M-m) : -(s/m)
                float l = (s > m) ? fmaf(s, inv_pd, c1) : s * ninv_m;
                if (dt && (lg * 4 + r == l16)) l = 1.0f;  // diag: exact 0 then +eye
                float q = a * l;
                bool gp = l > 0.f;
                float pos = gp ? l : q;
                float neg = -(gp ? q : l);
                myP[lg * 4 + r][jn * 16 + l16] = h2u((half_t)pos);
                myN[lg * 4 + r][jn * 16 + l16] = h2u((half_t)neg);
            }
        }
        // ---- PV: wave-private LDS read (no barrier), plain f16 MFMA ----
#pragma unroll
        for (int kc = 0; kc < 2; ++kc) {
            const ushort* pr = &myP[l16][kc * 32 + lg * 8];
            const ushort* nr = &myN[l16][kc * 32 + lg * 8];
            UH8 tp, tn;
            *(int2*)&tp.i       = *(const int2*)pr;
            *(((int2*)&tp.i)+1) = *(const int2*)(pr + 4);
            *(int2*)&tn.i       = *(const int2*)nr;
            *(((int2*)&tn.i)+1) = *(const int2*)(nr + 4);
            const int ecol = j0 + kc * 32 + lg * 8;
#pragma unroll
            for (int cs = 0; cs < 4; ++cs) {
                const size_t eo = (size_t)(cs * 16 + l16) * N + ecol;
                half8 Ef = ldh(Et + eo);
                accP[cs] = MFMA16(tp.h, Ef, accP[cs]);
                accN[cs] = MFMA16(tn.h, Ef, accN[cs]);
            }
        }
    }
    // ---- deterministic 4-wave combine: ((w0+w2) + (w1+w3)) ----
    __syncthreads();
    float* scr = (float*)&PNs[0][0][0][0];
    if (w >= 2) {
        float* base = scr + (size_t)(w - 2) * 2048;
#pragma unroll
        for (int cs = 0; cs < 4; ++cs)
#pragma unroll
            for (int r = 0; r < 4; ++r) {
                const int idx = (lg * 4 + r) * 64 + cs * 16 + l16;
                base[idx]        = accP[cs][r];
                base[idx + 1024] = accN[cs][r];
            }
    }
    __syncthreads();
    if (w < 2) {
        const float* src = scr + (size_t)w * 2048;
#pragma unroll
        for (int cs = 0; cs < 4; ++cs)
#pragma unroll
            for (int r = 0; r < 4; ++r) {
                const int idx = (lg * 4 + r) * 64 + cs * 16 + l16;
                accP[cs][r] += src[idx];
                accN[cs][r] += src[idx + 1024];
            }
    }
    __syncthreads();
    if (w == 1) {
#pragma unroll
        for (int cs = 0; cs < 4; ++cs)
#pragma unroll
            for (int r = 0; r < 4; ++r) {
                const int idx = (lg * 4 + r) * 64 + cs * 16 + l16;
                scr[idx]        = accP[cs][r];
                scr[idx + 1024] = accN[cs][r];
            }
    }
    __syncthreads();
    if (w == 0) {
#pragma unroll
        for (int cs = 0; cs < 4; ++cs)
#pragma unroll
            for (int r = 0; r < 4; ++r) {
                const int idx = (lg * 4 + r) * 64 + cs * 16 + l16;
                const size_t off = ((size_t)js * N + i0 + lg * 4 + r) * 64 + cs * 16 + l16;
                Pp[off] = accP[cs][r] + scr[idx];
                Pn[off] = accN[cs][r] + scr[idx + 1024];
            }
    }
}

// Reduce 4 partials, row-softmax both, combine with fp32 E.
__global__ __launch_bounds__(256) void fin_msg(
    const float* __restrict__ Pp, const float* __restrict__ Pn,
    const float* __restrict__ E, float* __restrict__ outm)
{
    const int w = threadIdx.x >> 6, lane = threadIdx.x & 63;
    const int row = blockIdx.x * 4 + w;
    float lp = 0.f, ln = 0.f;
#pragma unroll
    for (int js = 0; js < 4; ++js) {
        lp += Pp[((size_t)js * N + row) * 64 + lane];
        ln += Pn[((size_t)js * N + row) * 64 + lane];
    }
    float mp = wave_max(lp);
    float ep = expf(lp - mp);
    float tp = wave_sum(ep); tp = __shfl(tp, 0, 64);
    float sp = ep / tp;
    float mn = wave_max(ln);
    float en = expf(ln - mn);
    float tn = wave_sum(en); tn = __shfl(tn, 0, 64);
    float sn = en / tn;
    outm[(size_t)row * 64 + lane] = (sp - sn + E[(size_t)row * 64 + lane]) * 0.5f;
}

__global__ void init_stats(float* stats)
{
    if (threadIdx.x < 128) stats[threadIdx.x] = 0.f;
}

extern "C" void kernel_launch(void* const* d_in, const int* in_sizes, int n_in,
                              void* d_out, int out_size, void* d_ws, size_t ws_size,
                              hipStream_t stream)
{
    const float* ori = (const float*)d_in[0];
    const float* smo = (const float*)d_in[1];
    // d_in[2] processed_feature: unused. d_in[3] universal_re: unused (beta=0).
    const float* Ws1 = (const float*)d_in[4];
    const float* bs1 = (const float*)d_in[5];
    const float* Ws2 = (const float*)d_in[6];
    const float* bs2 = (const float*)d_in[7];
    const float* Wl1 = (const float*)d_in[8];
    const float* bl1 = (const float*)d_in[9];
    const float* Wl2 = (const float*)d_in[10];
    const float* bl2 = (const float*)d_in[11];
    const float* Wh1 = (const float*)d_in[12];
    const float* bh1 = (const float*)d_in[13];
    const float* Wh2 = (const float*)d_in[14];
    const float* bh2 = (const float*)d_in[15];
    const float* am  = (const float*)d_in[16];
    const float* ah  = (const float*)d_in[17];

    float* out_ori = (float*)d_out;
    float* out_smo = out_ori + (size_t)N * 64;
    float* out_msg = out_smo + (size_t)N * 64;

    char* p = (char*)d_ws;
    ushort* hh    = (ushort*)p; p += (size_t)N * 256 * 2;    // 4 MB
    ushort* hl    = (ushort*)p; p += (size_t)N * 256 * 2;    // 4 MB
    float* E      = (float*)p;  p += (size_t)N * 64 * 4;     // 2 MB
    float* Pp     = (float*)p;  p += (size_t)4 * N * 64 * 4; // 8 MB (aliases smoh)
    float* Pn     = (float*)p;  p += (size_t)4 * N * 64 * 4; // 8 MB (aliases smol)
    ushort* uh    = (ushort*)p; p += (size_t)N * 64 * 2;     // 1 MB
    ushort* ul    = (ushort*)p; p += (size_t)N * 64 * 2;     // 1 MB
    ushort* Et    = (ushort*)p; p += (size_t)N * 64 * 2;     // 1 MB
    ushort* orih  = (ushort*)p; p += (size_t)N * 128 * 2;    // 2 MB
    ushort* oril  = (ushort*)p; p += (size_t)N * 128 * 2;    // 2 MB
    ushort* Ws1h  = (ushort*)p; p += 256 * 512 * 2;          // weights split: ~1.2 MB
    ushort* Ws1l  = (ushort*)p; p += 256 * 512 * 2;
    ushort* Ws2h  = (ushort*)p; p += 64 * 256 * 2;
    ushort* Ws2l  = (ushort*)p; p += 64 * 256 * 2;
    ushort* Wl1h  = (ushort*)p; p += 256 * 128 * 2;
    ushort* Wl1l  = (ushort*)p; p += 256 * 128 * 2;
    ushort* Wl2h  = (ushort*)p; p += 64 * 256 * 2;
    ushort* Wl2l  = (ushort*)p; p += 64 * 256 * 2;
    ushort* Wh1h  = (ushort*)p; p += 256 * 512 * 2;
    ushort* Wh1l  = (ushort*)p; p += 256 * 512 * 2;
    ushort* Wh2h  = (ushort*)p; p += 64 * 256 * 2;
    ushort* Wh2l  = (ushort*)p; p += 64 * 256 * 2;
    float* maxbuf = (float*)p;  p += 1024 * 4;               // 4 KB
    float* stats  = (float*)p;                               // 128 floats
    // total ~34.2 MB
    // smoh/smol alias Pp/Pn: live from split until hete layer-1; Pp/Pn written
    // only by pass_prop_f16 (after smoh is dead).
    ushort* smoh = (ushort*)Pp;
    ushort* smol = (ushort*)Pn;

    const dim3 b(256);
    init_stats<<<1, 128, 0, stream>>>(stats);

    // ---- split inputs & weights to f16 pairs ----
    split_f16<<<4096, b, 0, stream>>>(smo, smoh, smol);
    split_f16<<<1024, b, 0, stream>>>(ori, orih, oril);
    split_f16<<<128,  b, 0, stream>>>(Ws1, Ws1h, Ws1l);
    split_f16<<<16,   b, 0, stream>>>(Ws2, Ws2h, Ws2l);
    split_f16<<<32,   b, 0, stream>>>(Wl1, Wl1h, Wl1l);
    split_f16<<<16,   b, 0, stream>>>(Wl2, Wl2h, Wl2l);
    split_f16<<<128,  b, 0, stream>>>(Wh1, Wh1h, Wh1l);
    split_f16<<<16,   b, 0, stream>>>(Wh2, Wh2h, Wh2l);

    const dim3 gb(128);
    // smooth path
    gemm_f16s<<<dim3(256, 4), gb, 0, stream>>>(smoh, smol, Ws1h, Ws1l, bs1, am,
                                               256, 512, 1, nullptr, hh, hl);
    gemm_f16s<<<dim3(256, 1), gb, 0, stream>>>(hh, hl, Ws2h, Ws2l, bs2, am,
                                               64, 256, 0, out_smo, nullptr, nullptr);
    // local path
    gemm_f16s<<<dim3(256, 4), gb, 0, stream>>>(orih, oril, Wl1h, Wl1l, bl1, am,
                                               256, 128, 1, nullptr, hh, hl);
    gemm_f16s<<<dim3(256, 1), gb, 0, stream>>>(hh, hl, Wl2h, Wl2l, bl2, am,
                                               64, 256, 0, out_ori, nullptr, nullptr);
    // hete path -> feature_emb E
    gemm_f16s<<<dim3(256, 4), gb, 0, stream>>>(smoh, smol, Wh1h, Wh1l, bh1, ah,
                                               256, 512, 1, nullptr, hh, hl);
    gemm_f16s<<<dim3(256, 1), gb, 0, stream>>>(hh, hl, Wh2h, Wh2l, bh2, ah,
                                               64, 256, 0, E, nullptr, nullptr);

    row_softmax_u<<<512, b, 0, stream>>>(E, uh, ul, stats);
    trans_e<<<128, b, 0, stream>>>(E, Et);
    pass_max_f16<<<dim3(128, 8), b, 0, stream>>>(uh, ul, maxbuf);
    fin_m<<<1, 256, 0, stream>>>(maxbuf, stats);
    pass_prop_f16<<<dim3(512, 4), b, 0, stream>>>(uh, ul, Et, stats, ah, Pp, Pn);
    fin_msg<<<2048, b, 0, stream>>>(Pp, Pn, E, out_msg);
}

// Round 8
// 811.165 us; speedup vs baseline: 1.0849x; 1.0849x over previous
//
#include <hip/hip_runtime.h>
#include <hip/hip_bf16.h>

#define N 8192

typedef _Float16 half_t;
typedef __attribute__((ext_vector_type(8))) _Float16 half8;
typedef __attribute__((ext_vector_type(4))) float f32x4;
typedef unsigned int uint;
typedef unsigned short ushort;

#define MFMA16(a, b, c) __builtin_amdgcn_mfma_f32_16x16x32_f16(a, b, c, 0, 0, 0)

// split: x = xh + xl * 2^-11 (residual stored x2048 to stay f16-normal)
#define RES_SCALE 2048.0f
#define RES_INV   (1.0f / 2048.0f)

union UH8 { int4 i; half8 h; };
__device__ __forceinline__ half8 ldh(const ushort* p) {
    UH8 t; t.i = *(const int4*)p; return t.h;
}
__device__ __forceinline__ ushort h2u(half_t h) {
    union { half_t f; ushort u; } c; c.f = h; return c.u;
}

__device__ __forceinline__ float wave_max(float v) {
#pragma unroll
    for (int o = 32; o > 0; o >>= 1) v = fmaxf(v, __shfl_xor(v, o, 64));
    return v;
}
__device__ __forceinline__ float wave_sum(float v) {
#pragma unroll
    for (int o = 32; o > 0; o >>= 1) v += __shfl_xor(v, o, 64);
    return v;
}

// ---------------------------------------------------------------------------
// Elementwise fp32 -> f16 split pair. n must be a multiple of 1024.
// ---------------------------------------------------------------------------
__global__ __launch_bounds__(256) void split_f16(
    const float* __restrict__ X, ushort* __restrict__ Xh, ushort* __restrict__ Xl)
{
    const size_t i = ((size_t)blockIdx.x * 256 + threadIdx.x) * 4;
    float4 v = *(const float4*)(X + i);
    ushort h[4], l[4];
#pragma unroll
    for (int t = 0; t < 4; ++t) {
        float f = (&v.x)[t];
        half_t hh = (half_t)f;
        half_t ll = (half_t)((f - (float)hh) * RES_SCALE);
        h[t] = h2u(hh); l[t] = h2u(ll);
    }
    *(ushort4*)(Xh + i) = make_ushort4(h[0], h[1], h[2], h[3]);
    *(ushort4*)(Xl + i) = make_ushort4(l[0], l[1], l[2], l[3]);
}

// ---------------------------------------------------------------------------
// Transpose the three 64x256 layer-2 weights to 256x64 fp32 (coalesced L2 GEMM).
// ---------------------------------------------------------------------------
__global__ __launch_bounds__(256) void trans_w2(
    const float* __restrict__ Ws2, const float* __restrict__ Wh2,
    const float* __restrict__ Wl2, float* __restrict__ Ts,
    float* __restrict__ Th, float* __restrict__ Tl)
{
    const int z = blockIdx.y;
    const float* in = z == 0 ? Ws2 : (z == 1 ? Wh2 : Wl2);
    float* out = z == 0 ? Ts : (z == 1 ? Th : Tl);
    const int idx = blockIdx.x * 256 + threadIdx.x;   // 0..16383
    const int k = idx >> 6, c = idx & 63;
    out[idx] = in[c * 256 + k];
}

// ---------------------------------------------------------------------------
// Merged layer-1 MLP GEMM: h_z = prelu(A_z @ W1_z^T + b1_z).
// f16 split-2 inputs, 3-term MFMA, fp32 out. Block = 256 thr / 4 waves:
// wave (w&1) picks 16-row half, (w>>1) picks K-half; LDS combine.
// Grid (M/32, 256/64, 3 paths) = (256,4,3) -> 12 blocks/CU.
// ---------------------------------------------------------------------------
__global__ __launch_bounds__(256) void gemm1_f16s(
    const ushort* __restrict__ smoh, const ushort* __restrict__ smol,
    const ushort* __restrict__ orih, const ushort* __restrict__ oril,
    const ushort* __restrict__ Ws1h, const ushort* __restrict__ Ws1l,
    const ushort* __restrict__ Wh1h, const ushort* __restrict__ Wh1l,
    const ushort* __restrict__ Wl1h, const ushort* __restrict__ Wl1l,
    const float* __restrict__ bs1, const float* __restrict__ bh1,
    const float* __restrict__ bl1, const float* __restrict__ am,
    const float* __restrict__ ah,
    float* __restrict__ h_s, float* __restrict__ h_h, float* __restrict__ h_l)
{
    const int z = blockIdx.z;
    const ushort *Ah, *Al, *Wh, *Wl;
    const float *bias, *slope;
    float* C;
    int K;
    if (z == 0)      { Ah = smoh; Al = smol; Wh = Ws1h; Wl = Ws1l; bias = bs1; slope = am; C = h_s; K = 512; }
    else if (z == 1) { Ah = smoh; Al = smol; Wh = Wh1h; Wl = Wh1l; bias = bh1; slope = ah; C = h_h; K = 512; }
    else             { Ah = orih; Al = oril; Wh = Wl1h; Wl = Wl1l; bias = bl1; slope = am; C = h_l; K = 128; }
    __shared__ float scr[2][16][64];
    const int w = threadIdx.x >> 6, lane = threadIdx.x & 63;
    const int l16 = lane & 15, lg = lane >> 4;
    const int row0 = blockIdx.x * 32 + (w & 1) * 16;
    const int n0 = blockIdx.y * 64;
    const int K2 = K >> 1;
    const int koff = (w >> 1) * K2;
    f32x4 acc1[4], acc2[4];
#pragma unroll
    for (int c = 0; c < 4; ++c) {
        acc1[c] = (f32x4){0.f, 0.f, 0.f, 0.f};
        acc2[c] = (f32x4){0.f, 0.f, 0.f, 0.f};
    }
    for (int k0 = 0; k0 < K2; k0 += 32) {
        const size_t aoff = (size_t)(row0 + l16) * K + koff + k0 + lg * 8;
        half8 Af = ldh(Ah + aoff);
        half8 Alf = ldh(Al + aoff);
#pragma unroll
        for (int c = 0; c < 4; ++c) {
            const size_t woff = (size_t)(n0 + c * 16 + l16) * K + koff + k0 + lg * 8;
            half8 Wf = ldh(Wh + woff);
            half8 Wlf = ldh(Wl + woff);
            acc1[c] = MFMA16(Af, Wf, acc1[c]);
            acc2[c] = MFMA16(Af, Wlf, acc2[c]);
            acc2[c] = MFMA16(Alf, Wf, acc2[c]);
        }
    }
    float v[4][4];
#pragma unroll
    for (int c = 0; c < 4; ++c)
#pragma unroll
        for (int r = 0; r < 4; ++r)
            v[c][r] = fmaf(acc2[c][r], RES_INV, acc1[c][r]);
    if (w >= 2) {
#pragma unroll
        for (int c = 0; c < 4; ++c)
#pragma unroll
            for (int r = 0; r < 4; ++r)
                scr[w & 1][lg * 4 + r][c * 16 + l16] = v[c][r];
    }
    __syncthreads();
    if (w < 2) {
        const float slp = *slope;
#pragma unroll
        for (int c = 0; c < 4; ++c) {
            const int col = n0 + c * 16 + l16;
            const float b = bias[col];
#pragma unroll
            for (int r = 0; r < 4; ++r) {
                const int row = row0 + lg * 4 + r;
                float val = v[c][r] + scr[w][lg * 4 + r][c * 16 + l16] + b;
                val = val > 0.f ? val : slp * val;
                C[(size_t)row * 256 + col] = val;
            }
        }
    }
}

// ---------------------------------------------------------------------------
// Merged layer-2 GEMM (fp32 VALU): out_z = h_z @ W2_z^T + b2_z.
// lane = output col (64), wave = 4 rows, block = 16 rows. Grid (512, 3).
// W2t is k-major [256][64] so lane loads are coalesced; h loads are
// wave-uniform (HW broadcast).
// ---------------------------------------------------------------------------
__global__ __launch_bounds__(256) void gemm2_val(
    const float* __restrict__ h_s, const float* __restrict__ h_h,
    const float* __restrict__ h_l, const float* __restrict__ Ts,
    const float* __restrict__ Th, const float* __restrict__ Tl,
    const float* __restrict__ bs2, const float* __restrict__ bh2,
    const float* __restrict__ bl2, float* __restrict__ out_smo,
    float* __restrict__ E, float* __restrict__ out_ori)
{
    const int z = blockIdx.y;
    const float *h, *Wt, *bias;
    float* out;
    if (z == 0)      { h = h_s; Wt = Ts; bias = bs2; out = out_smo; }
    else if (z == 1) { h = h_h; Wt = Th; bias = bh2; out = E; }
    else             { h = h_l; Wt = Tl; bias = bl2; out = out_ori; }
    const int w = threadIdx.x >> 6, lane = threadIdx.x & 63;
    const int row0 = blockIdx.x * 16 + w * 4;
    float acc[4] = {0.f, 0.f, 0.f, 0.f};
    for (int k0 = 0; k0 < 256; k0 += 4) {
        const float w0 = Wt[(k0 + 0) * 64 + lane];
        const float w1 = Wt[(k0 + 1) * 64 + lane];
        const float w2 = Wt[(k0 + 2) * 64 + lane];
        const float w3 = Wt[(k0 + 3) * 64 + lane];
#pragma unroll
        for (int r = 0; r < 4; ++r) {
            float4 hv = *(const float4*)(h + (size_t)(row0 + r) * 256 + k0);
            acc[r] = fmaf(hv.x, w0, acc[r]);
            acc[r] = fmaf(hv.y, w1, acc[r]);
            acc[r] = fmaf(hv.z, w2, acc[r]);
            acc[r] = fmaf(hv.w, w3, acc[r]);
        }
    }
    const float b = bias[lane];
#pragma unroll
    for (int r = 0; r < 4; ++r)
        out[(size_t)(row0 + r) * 64 + lane] = acc[r] + b;
}

// ---------------------------------------------------------------------------
// Row softmax + normalize; emit f16 2-way split of u; accumulate s, trace.
// ---------------------------------------------------------------------------
__global__ __launch_bounds__(256) void row_softmax_u(
    const float* __restrict__ E, ushort* __restrict__ uh, ushort* __restrict__ ul,
    float* __restrict__ stats)
{
    const int w = threadIdx.x >> 6, lane = threadIdx.x & 63;
    __shared__ float sacc[4][64];
    __shared__ float tacc[4];
    float s_l = 0.f, t_w = 0.f;
    const int base = blockIdx.x * 16 + w * 4;
    for (int r = 0; r < 4; ++r) {
        const int row = base + r;
        float v = E[(size_t)row * 64 + lane];
        float mx = wave_max(v);
        float e = expf(v - mx);
        float tot = wave_sum(e);
        tot = __shfl(tot, 0, 64);
        float es = e / tot;
        float dd = wave_sum(es * es);
        dd = __shfl(dd, 0, 64);
        float uv = es / sqrtf(dd);   // max(.,1e-9) never binds: dd >= 1/64
        half_t h = (half_t)uv;
        half_t l = (half_t)((uv - (float)h) * RES_SCALE);
        const size_t idx = (size_t)row * 64 + lane;
        uh[idx] = h2u(h); ul[idx] = h2u(l);
        s_l += uv;
        float uu = wave_sum(uv * uv);
        if (lane == 0) t_w += uu;
    }
    sacc[w][lane] = s_l;
    if (lane == 0) tacc[w] = t_w;
    __syncthreads();
    if (threadIdx.x < 64) {
        float tot = sacc[0][threadIdx.x] + sacc[1][threadIdx.x] +
                    sacc[2][threadIdx.x] + sacc[3][threadIdx.x];
        atomicAdd(&stats[threadIdx.x], tot);
    }
    if (threadIdx.x == 0)
        atomicAdd(&stats[64], tacc[0] + tacc[1] + tacc[2] + tacc[3]);
}

// ---------------------------------------------------------------------------
// Transpose E -> Et f16 [64][8192] so PV B-frags are direct 16B loads.
// ---------------------------------------------------------------------------
__global__ __launch_bounds__(256) void trans_e(
    const float* __restrict__ E, ushort* __restrict__ Et)
{
    __shared__ ushort T[64][72];
    const int ib = blockIdx.x;
    const int r = threadIdx.x >> 2;
    const int c0 = (threadIdx.x & 3) * 16;
#pragma unroll
    for (int q = 0; q < 4; ++q) {
        float4 v = *(const float4*)(E + (size_t)(ib * 64 + r) * 64 + c0 + q * 4);
#pragma unroll
        for (int t = 0; t < 4; ++t)
            T[c0 + q * 4 + t][r] = h2u((half_t)((&v.x)[t]));
    }
    __syncthreads();
    const int c = threadIdx.x >> 2;
    const int j0 = (threadIdx.x & 3) * 16;
    const size_t go = (size_t)c * N + ib * 64 + j0;
    *(int4*)(Et + go)     = *(const int4*)&T[c][j0];
    *(int4*)(Et + go + 8) = *(const int4*)&T[c][j0 + 8];
}

// ---------------------------------------------------------------------------
// Max over off-diagonal of S = u u^T. 4-wave blocks, triangle skip,
// per-block max -> maxbuf (no atomics).
// ---------------------------------------------------------------------------
__global__ __launch_bounds__(256) void pass_max_f16(
    const ushort* __restrict__ uh, const ushort* __restrict__ ul,
    float* __restrict__ maxbuf)
{
    const int bx = blockIdx.x;       // i-strip [0,128)
    const int by = blockIdx.y;       // j-group [0,8)
    const int bid = by * 128 + bx;
    const int w = threadIdx.x >> 6, lane = threadIdx.x & 63;
    const int l16 = lane & 15, lg = lane >> 4;
    __shared__ float red[4];
    if (by * 1024 + 1024 <= bx * 64) {   // whole block below diagonal
        if (threadIdx.x == 0) maxbuf[bid] = 0.f;
        return;
    }
    const int i0 = bx * 64 + w * 16;
    const size_t ao = (size_t)(i0 + l16) * 64 + lg * 8;
    const half8 Ah0 = ldh(uh + ao), Ah1 = ldh(uh + ao + 32);
    const half8 Al0 = ldh(ul + ao), Al1 = ldh(ul + ao + 32);
    float mx = 0.f;
    for (int jn = 0; jn < 64; ++jn) {
        const int j0 = by * 1024 + jn * 16;
        if (j0 + 16 <= i0) continue;     // tile fully below this wave's diagonal
        const size_t bo = (size_t)(j0 + l16) * 64 + lg * 8;
        half8 Bh0 = ldh(uh + bo), Bh1 = ldh(uh + bo + 32);
        half8 Bl0 = ldh(ul + bo), Bl1 = ldh(ul + bo + 32);
        f32x4 s1 = {0.f, 0.f, 0.f, 0.f};
        f32x4 s2 = {0.f, 0.f, 0.f, 0.f};
        s1 = MFMA16(Ah0, Bh0, s1); s1 = MFMA16(Ah1, Bh1, s1);
        s2 = MFMA16(Ah0, Bl0, s2); s2 = MFMA16(Ah1, Bl1, s2);
        s2 = MFMA16(Al0, Bh0, s2); s2 = MFMA16(Al1, Bh1, s2);
        const bool dt = (j0 == i0);
#pragma unroll
        for (int r = 0; r < 4; ++r) {
            float s = fmaf(s2[r], RES_INV, s1[r]);
            bool dg = dt && (lg * 4 + r == l16);
            mx = dg ? mx : fmaxf(mx, s);
        }
    }
    mx = wave_max(mx);
    if (lane == 0) red[w] = mx;
    __syncthreads();
    if (threadIdx.x == 0)
        maxbuf[bid] = fmaxf(fmaxf(red[0], red[1]), fmaxf(red[2], red[3]));
}

// Reduce block maxes -> M; m = (||s||^2 - trace) / N^2.
__global__ __launch_bounds__(256) void fin_m(
    const float* __restrict__ maxbuf, float* __restrict__ stats)
{
    const int t = threadIdx.x;
    float mx = 0.f;
    for (int i = t; i < 1024; i += 256) mx = fmaxf(mx, maxbuf[i]);
    mx = wave_max(mx);
    __shared__ float red[4];
    __shared__ float ssh;
    if ((t & 63) == 0) red[t >> 6] = mx;
    if (t < 64) {
        float s = stats[t];
        float ss = wave_sum(s * s);
        if (t == 0) ssh = ss;
    }
    __syncthreads();
    if (t == 0) {
        stats[65] = fmaxf(fmaxf(red[0], red[1]), fmaxf(red[2], red[3]));
        stats[66] = (ssh - stats[64]) * (1.0f / 67108864.0f);
    }
}

// ---------------------------------------------------------------------------
// Fused: S tiles (f16 split MFMA) -> transform -> P,N f16 -> wave-private LDS
// -> PV (plain f16 MFMA vs Et). Block = one 16-row i-tile x one js slice;
// 4 waves split the 32 jt, deterministic LDS combine at the end.
// NOTE: (256,4) only. (256,8) forces VGPR 56->32 and spills the accumulators
// to scratch: +370 MB WRITE_SIZE, 189->281 us (measured r7).
// ---------------------------------------------------------------------------
__global__ __launch_bounds__(256, 4) void pass_prop_f16(
    const ushort* __restrict__ uh, const ushort* __restrict__ ul,
    const ushort* __restrict__ Et, const float* __restrict__ stats,
    const float* __restrict__ ah_p, float* __restrict__ Pp, float* __restrict__ Pn)
{
    __shared__ ushort PNs[4][2][16][68];   // [wave][P/N][i-local][j-local], stride 68
    const int w = threadIdx.x >> 6, lane = threadIdx.x & 63;
    const int l16 = lane & 15, lg = lane >> 4;
    const int i0 = blockIdx.x * 16;
    const int js = blockIdx.y;
    const float m = stats[66];
    const float Mx = stats[65];
    const float inv_pd = 1.f / (Mx - m);
    const float c1 = -m * inv_pd;
    const float ninv_m = -1.f / m;
    const float a = *ah_p;
    const size_t ao = (size_t)(i0 + l16) * 64 + lg * 8;
    const half8 Ah0 = ldh(uh + ao), Ah1 = ldh(uh + ao + 32);
    const half8 Al0 = ldh(ul + ao), Al1 = ldh(ul + ao + 32);
    f32x4 accP[4], accN[4];
#pragma unroll
    for (int cs = 0; cs < 4; ++cs) {
        accP[cs] = (f32x4){0.f, 0.f, 0.f, 0.f};
        accN[cs] = (f32x4){0.f, 0.f, 0.f, 0.f};
    }
    ushort (*myP)[68] = PNs[w][0];
    ushort (*myN)[68] = PNs[w][1];
    for (int t = 0; t < 8; ++t) {
        const int j0 = (js * 32 + t * 4 + w) * 64;
        // ---- S tiles -> transform -> f16 P,N into wave-private LDS ----
#pragma unroll
        for (int jn = 0; jn < 4; ++jn) {
            const size_t bo = (size_t)(j0 + jn * 16 + l16) * 64 + lg * 8;
            half8 Bh0 = ldh(uh + bo), Bh1 = ldh(uh + bo + 32);
            half8 Bl0 = ldh(ul + bo), Bl1 = ldh(ul + bo + 32);
            f32x4 s1 = {0.f, 0.f, 0.f, 0.f};
            f32x4 s2 = {0.f, 0.f, 0.f, 0.f};
            s1 = MFMA16(Ah0, Bh0, s1); s1 = MFMA16(Ah1, Bh1, s1);
            s2 = MFMA16(Ah0, Bl0, s2); s2 = MFMA16(Ah1, Bl1, s2);
            s2 = MFMA16(Al0, Bh0, s2); s2 = MFMA16(Al1, Bh1, s2);
            const bool dt = (j0 + jn * 16 == i0);
#pragma unroll
            for (int r = 0; r < 4; ++r) {
                float s = fmaf(s2[r], RES_INV, s1[r]);
                // l = (s-m > 0) ? (s-m)/(M-m) : -(s/m)
                float l = (s > m) ? fmaf(s, inv_pd, c1) : s * ninv_m;
                if (dt && (lg * 4 + r == l16)) l = 1.0f;  // diag: exact 0 then +eye
                float q = a * l;
                bool gp = l > 0.f;
                float pos = gp ? l : q;
                float neg = -(gp ? q : l);
                myP[lg * 4 + r][jn * 16 + l16] = h2u((half_t)pos);
                myN[lg * 4 + r][jn * 16 + l16] = h2u((half_t)neg);
            }
        }
        // ---- PV: wave-private LDS read (no barrier), plain f16 MFMA ----
#pragma unroll
        for (int kc = 0; kc < 2; ++kc) {
            const ushort* pr = &myP[l16][kc * 32 + lg * 8];
            const ushort* nr = &myN[l16][kc * 32 + lg * 8];
            UH8 tp, tn;
            *(int2*)&tp.i       = *(const int2*)pr;
            *(((int2*)&tp.i)+1) = *(const int2*)(pr + 4);
            *(int2*)&tn.i       = *(const int2*)nr;
            *(((int2*)&tn.i)+1) = *(const int2*)(nr + 4);
            const int ecol = j0 + kc * 32 + lg * 8;
#pragma unroll
            for (int cs = 0; cs < 4; ++cs) {
                const size_t eo = (size_t)(cs * 16 + l16) * N + ecol;
                half8 Ef = ldh(Et + eo);
                accP[cs] = MFMA16(tp.h, Ef, accP[cs]);
                accN[cs] = MFMA16(tn.h, Ef, accN[cs]);
            }
        }
    }
    // ---- deterministic 4-wave combine: ((w0+w2) + (w1+w3)) ----
    __syncthreads();
    float* scr = (float*)&PNs[0][0][0][0];
    if (w >= 2) {
        float* base = scr + (size_t)(w - 2) * 2048;
#pragma unroll
        for (int cs = 0; cs < 4; ++cs)
#pragma unroll
            for (int r = 0; r < 4; ++r) {
                const int idx = (lg * 4 + r) * 64 + cs * 16 + l16;
                base[idx]        = accP[cs][r];
                base[idx + 1024] = accN[cs][r];
            }
    }
    __syncthreads();
    if (w < 2) {
        const float* src = scr + (size_t)w * 2048;
#pragma unroll
        for (int cs = 0; cs < 4; ++cs)
#pragma unroll
            for (int r = 0; r < 4; ++r) {
                const int idx = (lg * 4 + r) * 64 + cs * 16 + l16;
                accP[cs][r] += src[idx];
                accN[cs][r] += src[idx + 1024];
            }
    }
    __syncthreads();
    if (w == 1) {
#pragma unroll
        for (int cs = 0; cs < 4; ++cs)
#pragma unroll
            for (int r = 0; r < 4; ++r) {
                const int idx = (lg * 4 + r) * 64 + cs * 16 + l16;
                scr[idx]        = accP[cs][r];
                scr[idx + 1024] = accN[cs][r];
            }
    }
    __syncthreads();
    if (w == 0) {
#pragma unroll
        for (int cs = 0; cs < 4; ++cs)
#pragma unroll
            for (int r = 0; r < 4; ++r) {
                const int idx = (lg * 4 + r) * 64 + cs * 16 + l16;
                const size_t off = ((size_t)js * N + i0 + lg * 4 + r) * 64 + cs * 16 + l16;
                Pp[off] = accP[cs][r] + scr[idx];
                Pn[off] = accN[cs][r] + scr[idx + 1024];
            }
    }
}

// Reduce 4 partials, row-softmax both, combine with fp32 E.
__global__ __launch_bounds__(256) void fin_msg(
    const float* __restrict__ Pp, const float* __restrict__ Pn,
    const float* __restrict__ E, float* __restrict__ outm)
{
    const int w = threadIdx.x >> 6, lane = threadIdx.x & 63;
    const int row = blockIdx.x * 4 + w;
    float lp = 0.f, ln = 0.f;
#pragma unroll
    for (int js = 0; js < 4; ++js) {
        lp += Pp[((size_t)js * N + row) * 64 + lane];
        ln += Pn[((size_t)js * N + row) * 64 + lane];
    }
    float mp = wave_max(lp);
    float ep = expf(lp - mp);
    float tp = wave_sum(ep); tp = __shfl(tp, 0, 64);
    float sp = ep / tp;
    float mn = wave_max(ln);
    float en = expf(ln - mn);
    float tn = wave_sum(en); tn = __shfl(tn, 0, 64);
    float sn = en / tn;
    outm[(size_t)row * 64 + lane] = (sp - sn + E[(size_t)row * 64 + lane]) * 0.5f;
}

__global__ void init_stats(float* stats)
{
    if (threadIdx.x < 128) stats[threadIdx.x] = 0.f;
}

extern "C" void kernel_launch(void* const* d_in, const int* in_sizes, int n_in,
                              void* d_out, int out_size, void* d_ws, size_t ws_size,
                              hipStream_t stream)
{
    const float* ori = (const float*)d_in[0];
    const float* smo = (const float*)d_in[1];
    // d_in[2] processed_feature: unused. d_in[3] universal_re: unused (beta=0).
    const float* Ws1 = (const float*)d_in[4];
    const float* bs1 = (const float*)d_in[5];
    const float* Ws2 = (const float*)d_in[6];
    const float* bs2 = (const float*)d_in[7];
    const float* Wl1 = (const float*)d_in[8];
    const float* bl1 = (const float*)d_in[9];
    const float* Wl2 = (const float*)d_in[10];
    const float* bl2 = (const float*)d_in[11];
    const float* Wh1 = (const float*)d_in[12];
    const float* bh1 = (const float*)d_in[13];
    const float* Wh2 = (const float*)d_in[14];
    const float* bh2 = (const float*)d_in[15];
    const float* am  = (const float*)d_in[16];
    const float* ah  = (const float*)d_in[17];

    float* out_ori = (float*)d_out;
    float* out_smo = out_ori + (size_t)N * 64;
    float* out_msg = out_smo + (size_t)N * 64;

    char* p = (char*)d_ws;
    float* h_s    = (float*)p;  p += (size_t)N * 256 * 4;    // 8 MB
    float* h_h    = (float*)p;  p += (size_t)N * 256 * 4;    // 8 MB
    float* h_l    = (float*)p;  p += (size_t)N * 256 * 4;    // 8 MB
    float* E      = (float*)p;  p += (size_t)N * 64 * 4;     // 2 MB
    float* Pp     = (float*)p;  p += (size_t)4 * N * 64 * 4; // 8 MB (aliases smoh)
    float* Pn     = (float*)p;  p += (size_t)4 * N * 64 * 4; // 8 MB (aliases smol)
    ushort* uh    = (ushort*)p; p += (size_t)N * 64 * 2;     // 1 MB
    ushort* ul    = (ushort*)p; p += (size_t)N * 64 * 2;     // 1 MB
    ushort* Et    = (ushort*)p; p += (size_t)N * 64 * 2;     // 1 MB
    ushort* orih  = (ushort*)p; p += (size_t)N * 128 * 2;    // 2 MB
    ushort* oril  = (ushort*)p; p += (size_t)N * 128 * 2;    // 2 MB
    ushort* Ws1h  = (ushort*)p; p += 256 * 512 * 2;          // W1 splits ~1.1 MB
    ushort* Ws1l  = (ushort*)p; p += 256 * 512 * 2;
    ushort* Wh1h  = (ushort*)p; p += 256 * 512 * 2;
    ushort* Wh1l  = (ushort*)p; p += 256 * 512 * 2;
    ushort* Wl1h  = (ushort*)p; p += 256 * 128 * 2;
    ushort* Wl1l  = (ushort*)p; p += 256 * 128 * 2;
    float* W2ts   = (float*)p;  p += 256 * 64 * 4;           // W2 transposes 192 KB
    float* W2th   = (float*)p;  p += 256 * 64 * 4;
    float* W2tl   = (float*)p;  p += 256 * 64 * 4;
    float* maxbuf = (float*)p;  p += 1024 * 4;               // 4 KB
    float* stats  = (float*)p;                               // 128 floats
    // total ~50.5 MB
    // smoh/smol alias Pp/Pn: live from split until gemm1; Pp/Pn written only
    // by pass_prop_f16 (after smoh is dead).
    ushort* smoh = (ushort*)Pp;
    ushort* smol = (ushort*)Pn;

    const dim3 b(256);
    init_stats<<<1, 128, 0, stream>>>(stats);

    // ---- prep: splits + W2 transpose ----
    split_f16<<<4096, b, 0, stream>>>(smo, smoh, smol);
    split_f16<<<1024, b, 0, stream>>>(ori, orih, oril);
    split_f16<<<128,  b, 0, stream>>>(Ws1, Ws1h, Ws1l);
    split_f16<<<128,  b, 0, stream>>>(Wh1, Wh1h, Wh1l);
    split_f16<<<32,   b, 0, stream>>>(Wl1, Wl1h, Wl1l);
    trans_w2<<<dim3(64, 3), b, 0, stream>>>(Ws2, Wh2, Wl2, W2ts, W2th, W2tl);

    // ---- MLPs: merged layer-1 (MFMA split) + merged layer-2 (VALU fp32) ----
    gemm1_f16s<<<dim3(256, 4, 3), b, 0, stream>>>(
        smoh, smol, orih, oril, Ws1h, Ws1l, Wh1h, Wh1l, Wl1h, Wl1l,
        bs1, bh1, bl1, am, ah, h_s, h_h, h_l);
    gemm2_val<<<dim3(512, 3), b, 0, stream>>>(
        h_s, h_h, h_l, W2ts, W2th, W2tl, bs2, bh2, bl2, out_smo, E, out_ori);

    // ---- propagation ----
    row_softmax_u<<<512, b, 0, stream>>>(E, uh, ul, stats);
    trans_e<<<128, b, 0, stream>>>(E, Et);
    pass_max_f16<<<dim3(128, 8), b, 0, stream>>>(uh, ul, maxbuf);
    fin_m<<<1, 256, 0, stream>>>(maxbuf, stats);
    pass_prop_f16<<<dim3(512, 4), b, 0, stream>>>(uh, ul, Et, stats, ah, Pp, Pn);
    fin_msg<<<2048, b, 0, stream>>>(Pp, Pn, E, out_msg);
}